// Round 1
// baseline (2874.576 us; speedup 1.0000x reference)
//
#include <hip/hip_runtime.h>
#include <hip/hip_bf16.h>

// EncoderGRUODE on MI355X.
// Design: 32 blocks x 512 threads; block owns 16 batch rows; 8 waves each own a
// 32-col slice of every gate. Recurrence weights stream from L2 each step in
// pre-packed MFMA-fragment order; w_ih cached in LDS; h crosses waves via LDS
// bf16 fragment buffers; fp32 master h in registers. Early exit at per-block
// max sequence length. Final w_out GEMM uses bf16 hi/lo split (~fp32 accurate).

#define Bn 512
#define Tn 256
#define Dn 64
#define Hn 256

typedef __bf16 bf16x8 __attribute__((ext_vector_type(8)));
typedef float f32x4 __attribute__((ext_vector_type(4)));

__device__ __forceinline__ f32x4 mfma_bf16(bf16x8 a, bf16x8 b, f32x4 c) {
  return __builtin_amdgcn_mfma_f32_16x16x32_bf16(a, b, c, 0, 0, 0);
}
__device__ __forceinline__ float fast_sigmoid(float x) {
  return __builtin_amdgcn_rcpf(1.0f + __expf(-x));
}
__device__ __forceinline__ float fast_tanh(float x) {
  return 1.0f - 2.0f * __builtin_amdgcn_rcpf(1.0f + __expf(2.0f * x));
}

// Pack [N][K] fp32 row-major -> bf16 MFMA-B-fragment order:
// element (n,k) -> [((n/16)*(K/32) + k/32)*64 + (n%16) + 16*((k%32)/8)]*8 + k%8
__global__ void pack_w(const float* __restrict__ w, __bf16* __restrict__ out,
                       int N, int K) {
  int idx = blockIdx.x * blockDim.x + threadIdx.x;
  if (idx >= N * K) return;
  int n = idx / K, k = idx % K;
  int tile = n >> 4, kb = k >> 5;
  int lane = (n & 15) + (((k & 31) >> 3) << 4);
  int j = k & 7;
  out[(((tile * (K >> 5) + kb) << 6) + lane) * 8 + j] = (__bf16)w[idx];
}

__global__ void pack_w_hilo(const float* __restrict__ w, __bf16* __restrict__ hi,
                            __bf16* __restrict__ lo, int N, int K) {
  int idx = blockIdx.x * blockDim.x + threadIdx.x;
  if (idx >= N * K) return;
  int n = idx / K, k = idx % K;
  int tile = n >> 4, kb = k >> 5;
  int lane = (n & 15) + (((k & 31) >> 3) << 4);
  int j = k & 7;
  int o = (((tile * (K >> 5) + kb) << 6) + lane) * 8 + j;
  float f = w[idx];
  __bf16 h = (__bf16)f;
  hi[o] = h;
  lo[o] = (__bf16)(f - (float)h);
}

__launch_bounds__(512)
__global__ void gru_ode_kernel(
    const float* __restrict__ x, const float* __restrict__ tps,
    const float* __restrict__ mask,
    const float* __restrict__ b_ih, const float* __restrict__ b_hh,
    const float* __restrict__ b1, const float* __restrict__ b2,
    const float* __restrict__ b_out,
    const __bf16* __restrict__ w1p, const __bf16* __restrict__ w2p,
    const __bf16* __restrict__ whhp, const __bf16* __restrict__ wihp,
    const __bf16* __restrict__ wouth, const __bf16* __restrict__ woutl,
    float* __restrict__ out) {
  __shared__ __align__(16) __bf16 h_fr[4096];   // h_new frags   [kb8][lane64][8]
  __shared__ __align__(16) __bf16 a_fr[4096];   // tanh() frags
  __shared__ __align__(16) __bf16 o_fr[4096];   // h_ode frags
  __shared__ __align__(16) __bf16 wih_l[49152]; // w_ih packed, 96KB
  __shared__ __align__(16) float hlast[16][260];
  __shared__ float tps_s[Tn];
  __shared__ int len_s[16];
  __shared__ int maxlen_s;

  const int tid = threadIdx.x;
  const int wv = tid >> 6;   // wave 0..7: owns cols [32*wv, 32*wv+32)
  const int l = tid & 63;
  const int g = l >> 4;      // lane k-group
  const int c = l & 15;      // lane row/col-in-tile
  const int m0 = blockIdx.x << 4;

  if (tid < Tn) tps_s[tid] = tps[tid];
#pragma unroll
  for (int i = 0; i < 8; i++) o_fr[tid + i * 512] = (__bf16)0.0f;
  {
    const int4* s4 = (const int4*)wihp;
    int4* d4 = (int4*)wih_l;
    for (int i = tid; i < 6144; i += 512) d4[i] = s4[i];
  }
  {
    int m = tid >> 5, l32 = tid & 31;
    const float* mr = mask + (size_t)(m0 + m) * Tn + l32 * 8;
    float s = 0.f;
#pragma unroll
    for (int i = 0; i < 8; i++) s += mr[i];
#pragma unroll
    for (int o = 16; o; o >>= 1) s += __shfl_down(s, o, 32);
    if (l32 == 0) len_s[m] = (int)(s + 0.5f);
  }
  __syncthreads();
  if (tid == 0) {
    int mx = 1;
    for (int i = 0; i < 16; i++) mx = max(mx, len_s[i]);
    maxlen_s = mx;
  }
  __syncthreads();
  const int maxlen = maxlen_s;
  int len4[4];
#pragma unroll
  for (int r = 0; r < 4; r++) len4[r] = len_s[4 * g + r];

  float bb1[2], bb2[2], brz[4], bin[2], bhn[2], bo[2];
#pragma unroll
  for (int nt = 0; nt < 2; nt++) {
    int col = 32 * wv + 16 * nt + c;
    bb1[nt] = b1[col];
    bb2[nt] = b2[col];
    brz[nt] = b_ih[col] + b_hh[col];
    brz[2 + nt] = b_ih[256 + col] + b_hh[256 + col];
    bin[nt] = b_ih[512 + col];
    bhn[nt] = b_hh[512 + col];
    bo[nt] = b_out[col];
  }

  float hreg[2][4] = {{0, 0, 0, 0}, {0, 0, 0, 0}}; // fp32 master h slice

  const bf16x8* w1f = (const bf16x8*)w1p;
  const bf16x8* w2f = (const bf16x8*)w2p;
  const bf16x8* whf = (const bf16x8*)whhp;
  const bf16x8* wif = (const bf16x8*)wih_l;

  // scatter-write base: (wv*64 + 4g + r + 32nt + 16*(c>>3))*8 + (c&7)
  const int wbase = (wv * 64 + 4 * g + 16 * (c >> 3)) * 8 + (c & 7);

  for (int t = 0; t < maxlen; t++) {
    // prefetch x fragment early (consumed in phase C)
    const float* xp = x + (size_t)(m0 + c) * (Tn * Dn) + t * Dn + 8 * g;
    f32x4 xr0 = *(const f32x4*)(xp);
    f32x4 xr1 = *(const f32x4*)(xp + 4);
    f32x4 xr2 = *(const f32x4*)(xp + 32);
    f32x4 xr3 = *(const f32x4*)(xp + 36);

    if (t > 0) {
      // ---- Phase A: a = tanh(h @ w1^T + b1)
      bf16x8 hf[8];
#pragma unroll
      for (int kb = 0; kb < 8; kb++) hf[kb] = *(const bf16x8*)&h_fr[(kb * 64 + l) * 8];
#pragma unroll
      for (int nt = 0; nt < 2; nt++) {
        f32x4 acc = {0.f, 0.f, 0.f, 0.f};
#pragma unroll
        for (int kb = 0; kb < 8; kb++)
          acc = mfma_bf16(hf[kb], w1f[((2 * wv + nt) * 8 + kb) * 64 + l], acc);
#pragma unroll
        for (int r = 0; r < 4; r++)
          a_fr[wbase + (r + 32 * nt) * 8] = (__bf16)fast_tanh(acc[r] + bb1[nt]);
      }
      __syncthreads();
      // ---- Phase B: h_ode = h + dt * (a @ w2^T + b2)
      float dtv = tps_s[t] - tps_s[t - 1];
      bf16x8 af[8];
#pragma unroll
      for (int kb = 0; kb < 8; kb++) af[kb] = *(const bf16x8*)&a_fr[(kb * 64 + l) * 8];
#pragma unroll
      for (int nt = 0; nt < 2; nt++) {
        f32x4 acc = {0.f, 0.f, 0.f, 0.f};
#pragma unroll
        for (int kb = 0; kb < 8; kb++)
          acc = mfma_bf16(af[kb], w2f[((2 * wv + nt) * 8 + kb) * 64 + l], acc);
#pragma unroll
        for (int r = 0; r < 4; r++) {
          hreg[nt][r] += dtv * (acc[r] + bb2[nt]);
          o_fr[wbase + (r + 32 * nt) * 8] = (__bf16)hreg[nt][r];
        }
      }
      __syncthreads();
    }
    // ---- Phase C: GRU cell on h_ode
    bf16x8 of[8];
#pragma unroll
    for (int kb = 0; kb < 8; kb++) of[kb] = *(const bf16x8*)&o_fr[(kb * 64 + l) * 8];
    bf16x8 xf0, xf1;
#pragma unroll
    for (int j = 0; j < 4; j++) {
      xf0[j] = (__bf16)xr0[j]; xf0[4 + j] = (__bf16)xr1[j];
      xf1[j] = (__bf16)xr2[j]; xf1[4 + j] = (__bf16)xr3[j];
    }
    f32x4 arz[4], agi[2], agh[2];
#pragma unroll
    for (int q = 0; q < 4; q++) { // q = gate*2+nt, gate 0=r 1=z
      int gate = q >> 1, nt = q & 1;
      int tile = (gate << 4) + 2 * wv + nt;
      f32x4 acc = {0.f, 0.f, 0.f, 0.f};
      acc = mfma_bf16(xf0, wif[(tile * 2 + 0) * 64 + l], acc);
      acc = mfma_bf16(xf1, wif[(tile * 2 + 1) * 64 + l], acc);
#pragma unroll
      for (int kb = 0; kb < 8; kb++)
        acc = mfma_bf16(of[kb], whf[(tile * 8 + kb) * 64 + l], acc);
      arz[q] = acc;
    }
#pragma unroll
    for (int nt = 0; nt < 2; nt++) { // n gate: keep gi / gh separate
      int tile = 32 + 2 * wv + nt;
      f32x4 ai = {0.f, 0.f, 0.f, 0.f}, ah = {0.f, 0.f, 0.f, 0.f};
      ai = mfma_bf16(xf0, wif[(tile * 2 + 0) * 64 + l], ai);
      ai = mfma_bf16(xf1, wif[(tile * 2 + 1) * 64 + l], ai);
#pragma unroll
      for (int kb = 0; kb < 8; kb++)
        ah = mfma_bf16(of[kb], whf[(tile * 8 + kb) * 64 + l], ah);
      agi[nt] = ai;
      agh[nt] = ah;
    }
#pragma unroll
    for (int nt = 0; nt < 2; nt++) {
#pragma unroll
      for (int r = 0; r < 4; r++) {
        float rg = fast_sigmoid(arz[nt][r] + brz[nt]);
        float zg = fast_sigmoid(arz[2 + nt][r] + brz[2 + nt]);
        float ng = fast_tanh(agi[nt][r] + bin[nt] + rg * (agh[nt][r] + bhn[nt]));
        float hn = (1.f - zg) * ng + zg * hreg[nt][r];
        hreg[nt][r] = hn;
        if (t == len4[r] - 1) hlast[4 * g + r][32 * wv + 16 * nt + c] = hn;
        h_fr[wbase + (r + 32 * nt) * 8] = (__bf16)hn;
      }
    }
    __syncthreads();
  }

  // ---- Output: out = h_last @ w_out^T + b_out (bf16 hi/lo split, ~fp32)
  const bf16x8* woh = (const bf16x8*)wouth;
  const bf16x8* wol = (const bf16x8*)woutl;
  f32x4 oa[2] = {{0.f, 0.f, 0.f, 0.f}, {0.f, 0.f, 0.f, 0.f}};
#pragma unroll
  for (int kb = 0; kb < 8; kb++) {
    f32x4 v0 = *(const f32x4*)&hlast[c][kb * 32 + 8 * g];
    f32x4 v1 = *(const f32x4*)&hlast[c][kb * 32 + 8 * g + 4];
    bf16x8 hhi, hlo;
#pragma unroll
    for (int j = 0; j < 4; j++) {
      __bf16 p = (__bf16)v0[j]; hhi[j] = p; hlo[j] = (__bf16)(v0[j] - (float)p);
      __bf16 q = (__bf16)v1[j]; hhi[4 + j] = q; hlo[4 + j] = (__bf16)(v1[j] - (float)q);
    }
#pragma unroll
    for (int nt = 0; nt < 2; nt++) {
      int tile = 2 * wv + nt;
      oa[nt] = mfma_bf16(hhi, woh[(tile * 8 + kb) * 64 + l], oa[nt]);
      oa[nt] = mfma_bf16(hlo, woh[(tile * 8 + kb) * 64 + l], oa[nt]);
      oa[nt] = mfma_bf16(hhi, wol[(tile * 8 + kb) * 64 + l], oa[nt]);
    }
  }
#pragma unroll
  for (int nt = 0; nt < 2; nt++)
#pragma unroll
    for (int r = 0; r < 4; r++)
      out[(size_t)(m0 + 4 * g + r) * Hn + 32 * wv + 16 * nt + c] = oa[nt][r] + bo[nt];
}

extern "C" void kernel_launch(void* const* d_in, const int* in_sizes, int n_in,
                              void* d_out, int out_size, void* d_ws, size_t ws_size,
                              hipStream_t stream) {
  const float* x = (const float*)d_in[0];
  const float* tps = (const float*)d_in[1];
  const float* mask = (const float*)d_in[2];
  const float* w_ih = (const float*)d_in[3];
  const float* w_hh = (const float*)d_in[4];
  const float* b_ih = (const float*)d_in[5];
  const float* b_hh = (const float*)d_in[6];
  const float* w1 = (const float*)d_in[7];
  const float* b1 = (const float*)d_in[8];
  const float* w2 = (const float*)d_in[9];
  const float* b2 = (const float*)d_in[10];
  const float* w_out = (const float*)d_in[11];
  const float* b_out = (const float*)d_in[12];

  char* ws = (char*)d_ws;
  __bf16* w1p = (__bf16*)(ws + 0);        // 131072 B
  __bf16* w2p = (__bf16*)(ws + 131072);   // 131072 B
  __bf16* whhp = (__bf16*)(ws + 262144);  // 393216 B
  __bf16* wihp = (__bf16*)(ws + 655360);  // 98304 B
  __bf16* wouth = (__bf16*)(ws + 753664); // 131072 B
  __bf16* woutl = (__bf16*)(ws + 884736); // 131072 B  (total < 1 MB)

  pack_w<<<(256 * 256 + 255) / 256, 256, 0, stream>>>(w1, w1p, 256, 256);
  pack_w<<<(256 * 256 + 255) / 256, 256, 0, stream>>>(w2, w2p, 256, 256);
  pack_w<<<(768 * 256 + 255) / 256, 256, 0, stream>>>(w_hh, whhp, 768, 256);
  pack_w<<<(768 * 64 + 255) / 256, 256, 0, stream>>>(w_ih, wihp, 768, 64);
  pack_w_hilo<<<(256 * 256 + 255) / 256, 256, 0, stream>>>(w_out, wouth, woutl, 256, 256);

  gru_ode_kernel<<<32, 512, 0, stream>>>(x, tps, mask, b_ih, b_hh, b1, b2, b_out,
                                         w1p, w2p, whhp, wihp, wouth, woutl,
                                         (float*)d_out);
}

// Round 2
// 2666.013 us; speedup vs baseline: 1.0782x; 1.0782x over previous
//
#include <hip/hip_runtime.h>
#include <hip/hip_bf16.h>

// EncoderGRUODE on MI355X — round 2.
// 32 blocks x 512 threads (8 waves); wave owns a 32-col slice of all gates.
// w1/w2 register-resident (loaded once). whh+wih+x stream from L2 via a
// 16-position global_load_lds ring (4 ops/pos, 3 LDS slots, lookahead 3,
// uniform s_waitcnt vmcnt(8) — never drained). Raw s_barrier + lgkmcnt(0)
// for fragment handoffs so barriers never drain vmcnt; the ring stays full
// across steps (weights are step-invariant, so wrapped issues just reload
// the same addresses). No other VMEM ops inside the loop -> vmcnt counting
// is sound (registers kept < 256 to avoid scratch spills, which would
// poison the count).

#define Bn 512
#define Tn 256
#define Dn 64
#define Hn 256

typedef __bf16 bf16x8 __attribute__((ext_vector_type(8)));
typedef float f32x4 __attribute__((ext_vector_type(4)));

__device__ __forceinline__ f32x4 mfma_bf16(bf16x8 a, bf16x8 b, f32x4 c) {
  return __builtin_amdgcn_mfma_f32_16x16x32_bf16(a, b, c, 0, 0, 0);
}
__device__ __forceinline__ float fast_sigmoid(float x) {
  return __builtin_amdgcn_rcpf(1.0f + __expf(-x));
}
__device__ __forceinline__ float fast_tanh(float x) {
  return 1.0f - 2.0f * __builtin_amdgcn_rcpf(1.0f + __expf(2.0f * x));
}

// async global->LDS, 16B per lane. dst is the wave-uniform base; HW adds lane*16.
__device__ __forceinline__ void gld16(const void* g, void* l) {
  __builtin_amdgcn_global_load_lds((const __attribute__((address_space(1))) void*)g,
                                   (__attribute__((address_space(3))) void*)l, 16, 0, 0);
}

// Pack [N][K] fp32 row-major -> bf16 MFMA-B-fragment order:
// element (n,k) -> [((n/16)*(K/32) + k/32)*64 + (n%16) + 16*((k%32)/8)]*8 + k%8
__global__ void pack_w(const float* __restrict__ w, __bf16* __restrict__ out,
                       int N, int K) {
  int idx = blockIdx.x * blockDim.x + threadIdx.x;
  if (idx >= N * K) return;
  int n = idx / K, k = idx % K;
  int tile = n >> 4, kb = k >> 5;
  int lane = (n & 15) + (((k & 31) >> 3) << 4);
  int j = k & 7;
  out[(((tile * (K >> 5) + kb) << 6) + lane) * 8 + j] = (__bf16)w[idx];
}

__global__ void pack_w_hilo(const float* __restrict__ w, __bf16* __restrict__ hi,
                            __bf16* __restrict__ lo, int N, int K) {
  int idx = blockIdx.x * blockDim.x + threadIdx.x;
  if (idx >= N * K) return;
  int n = idx / K, k = idx % K;
  int tile = n >> 4, kb = k >> 5;
  int lane = (n & 15) + (((k & 31) >> 3) << 4);
  int j = k & 7;
  int o = (((tile * (K >> 5) + kb) << 6) + lane) * 8 + j;
  float f = w[idx];
  __bf16 h = (__bf16)f;
  hi[o] = h;
  lo[o] = (__bf16)(f - (float)h);
}

#define RING_WAIT()                                          \
  asm volatile("s_waitcnt vmcnt(8)" ::: "memory");           \
  __builtin_amdgcn_sched_barrier(0);

#define BAR()                                                \
  asm volatile("s_waitcnt lgkmcnt(0)" ::: "memory");         \
  __builtin_amdgcn_sched_barrier(0);                         \
  __builtin_amdgcn_s_barrier();                              \
  __builtin_amdgcn_sched_barrier(0);

// Issue weight chunk k (0..14): 4 gl_lds of one 4-fragment chunk into slot k%3.
#define ISSUE_W(k)                                                             \
  {                                                                            \
    __bf16* db_ = slots + ((k) % 3) * 16384 + wv * 2048;                       \
    if ((k) < 12) {                                                            \
      const int tile_ = ((k) >> 2) * 16 + 2 * wv + (((k) & 3) >> 1);           \
      const int kb0_ = ((k) & 1) * 4;                                          \
      _Pragma("unroll") for (int f_ = 0; f_ < 4; f_++)                         \
          gld16(whh_lane + (tile_ * 8 + kb0_ + f_) * 512, db_ + f_ * 512);     \
    } else {                                                                   \
      const int gg_ = (k) - 12;                                                \
      _Pragma("unroll") for (int f_ = 0; f_ < 4; f_++) {                       \
        const int tile_ = gg_ * 16 + 2 * wv + (f_ >> 1);                       \
        gld16(wih_lane + (tile_ * 2 + (f_ & 1)) * 512, db_ + f_ * 512);        \
      }                                                                        \
    }                                                                          \
  }

// Issue x tile for timestep tt (clamped) into xbuf[tt&1]: 4 gl_lds, per-lane src.
#define ISSUE_X(tt)                                                            \
  {                                                                            \
    const int t2_ = ((tt) < Tn) ? (tt) : Tn - 1;                               \
    const float* xs_ = x_lane + t2_ * 64;                                      \
    float* xd_ = &xbuf[(tt) & 1][0];                                           \
    _Pragma("unroll") for (int f_ = 0; f_ < 4; f_++)                           \
        gld16(xs_ + f_ * 16, xd_ + f_ * 256);                                  \
  }

__launch_bounds__(512, 2)
__global__ void gru_ode_kernel(
    const float* __restrict__ x, const float* __restrict__ tps,
    const float* __restrict__ mask,
    const float* __restrict__ b_ih, const float* __restrict__ b_hh,
    const float* __restrict__ b1, const float* __restrict__ b2,
    const float* __restrict__ b_out,
    const __bf16* __restrict__ w1p, const __bf16* __restrict__ w2p,
    const __bf16* __restrict__ whhp, const __bf16* __restrict__ wihp,
    const __bf16* __restrict__ wouth, const __bf16* __restrict__ woutl,
    float* __restrict__ out) {
  __shared__ __align__(16) __bf16 slots[49152];  // 3 ring slots x 32KB = 96KB
  __shared__ __align__(16) __bf16 h_fr[4096];    // h_new fragments [kb8][lane64][8]
  __shared__ __align__(16) __bf16 a_fr[4096];    // tanh() fragments
  __shared__ __align__(16) __bf16 o_fr[4096];    // h_ode fragments
  __shared__ __align__(16) float xbuf[2][1024];  // x tile dbuf, [d4 16][row 16][4]
  __shared__ __align__(16) float hlast[16][260];
  __shared__ float dt_s[Tn];
  __shared__ int len_s[16];
  __shared__ int maxlen_s;

  const int tid = threadIdx.x;
  const int wv = tid >> 6;  // wave 0..7: owns cols [32*wv, 32*wv+32)
  const int l = tid & 63;
  const int g = l >> 4;   // lane k-group
  const int c = l & 15;   // lane row/col-in-tile
  const int m0 = blockIdx.x << 4;

  if (tid < Tn) dt_s[tid] = tid ? tps[tid] - tps[tid - 1] : 0.01f;
#pragma unroll
  for (int i = 0; i < 8; i++) o_fr[tid + i * 512] = (__bf16)0.0f;
  {
    int m = tid >> 5, l32 = tid & 31;
    const float* mr = mask + (size_t)(m0 + m) * Tn + l32 * 8;
    float s = 0.f;
#pragma unroll
    for (int i = 0; i < 8; i++) s += mr[i];
#pragma unroll
    for (int o = 16; o; o >>= 1) s += __shfl_down(s, o, 32);
    if (l32 == 0) len_s[m] = (int)(s + 0.5f);
  }
  __syncthreads();
  if (tid == 0) {
    int mx = 1;
    for (int i = 0; i < 16; i++) mx = max(mx, len_s[i]);
    maxlen_s = mx;
  }
  __syncthreads();
  const int maxlen = maxlen_s;
  int len4[4];
#pragma unroll
  for (int r = 0; r < 4; r++) len4[r] = len_s[4 * g + r];

  float bb1[2], bb2[2], brz[4], bin[2], bhn[2], bo[2];
#pragma unroll
  for (int nt = 0; nt < 2; nt++) {
    int col = 32 * wv + 16 * nt + c;
    bb1[nt] = b1[col];
    bb2[nt] = b2[col];
    brz[nt] = b_ih[col] + b_hh[col];
    brz[2 + nt] = b_ih[256 + col] + b_hh[256 + col];
    bin[nt] = b_ih[512 + col];
    bhn[nt] = b_hh[512 + col];
    bo[nt] = b_out[col];
  }

  // Resident w1/w2 fragments (loaded once; 128 VGPRs).
  bf16x8 w1f[2][8], w2f[2][8];
#pragma unroll
  for (int nt = 0; nt < 2; nt++)
#pragma unroll
    for (int kb = 0; kb < 8; kb++) {
      w1f[nt][kb] = *(const bf16x8*)&w1p[(((2 * wv + nt) * 8 + kb) * 64 + l) * 8];
      w2f[nt][kb] = *(const bf16x8*)&w2p[(((2 * wv + nt) * 8 + kb) * 64 + l) * 8];
    }

  float hreg[2][4] = {{0, 0, 0, 0}, {0, 0, 0, 0}};  // fp32 master h slice

  // Per-lane stream base addresses.
  const __bf16* whh_lane = whhp + l * 8;
  const __bf16* wih_lane = wihp + l * 8;
  const float* x_lane = x + (size_t)(m0 + (l & 15)) * (Tn * Dn) + (l >> 4) * 4;

  // scatter-write base: (wv*64 + 4g + 32nt + 16*(c>>3) + r)*8 + (c&7)
  const int wbase = (wv * 64 + 4 * g + 16 * (c >> 3)) * 8 + (c & 7);

  // ---- Ring prologue: x(0), drain, then 3 weight chunks in flight.
  ISSUE_X(0);
  asm volatile("s_waitcnt vmcnt(0)" ::: "memory");
  __builtin_amdgcn_sched_barrier(0);
  ISSUE_W(0);
  ISSUE_W(1);
  ISSUE_W(2);

  bf16x8 xf0, xf1;

  for (int t = 0; t < maxlen; t++) {
    if (t > 0) {
      // ---- Phase A: a = tanh(h @ w1^T + b1)  (register-resident w1)
      {
        bf16x8 hfv[8];
#pragma unroll
        for (int kb = 0; kb < 8; kb++)
          hfv[kb] = *(const bf16x8*)&h_fr[(kb * 64 + l) * 8];
#pragma unroll
        for (int nt = 0; nt < 2; nt++) {
          f32x4 acc = {0.f, 0.f, 0.f, 0.f};
#pragma unroll
          for (int kb = 0; kb < 8; kb++) acc = mfma_bf16(hfv[kb], w1f[nt][kb], acc);
#pragma unroll
          for (int r = 0; r < 4; r++)
            a_fr[wbase + (r + 32 * nt) * 8] = (__bf16)fast_tanh(acc[r] + bb1[nt]);
        }
      }
      BAR();
      // ---- Phase B: h_ode = h + dt * (a @ w2^T + b2)  (register-resident w2)
      {
        const float dtv = dt_s[t];
        bf16x8 afv[8];
#pragma unroll
        for (int kb = 0; kb < 8; kb++)
          afv[kb] = *(const bf16x8*)&a_fr[(kb * 64 + l) * 8];
#pragma unroll
        for (int nt = 0; nt < 2; nt++) {
          f32x4 acc = {0.f, 0.f, 0.f, 0.f};
#pragma unroll
          for (int kb = 0; kb < 8; kb++) acc = mfma_bf16(afv[kb], w2f[nt][kb], acc);
#pragma unroll
          for (int r = 0; r < 4; r++) {
            hreg[nt][r] += dtv * (acc[r] + bb2[nt]);
            o_fr[wbase + (r + 32 * nt) * 8] = (__bf16)hreg[nt][r];
          }
        }
      }
      BAR();
    }

    // ---- Phase C: GRU cell on h_ode — 16-position stream ring.
    // acc6: r_nt0, r_nt1, z_nt0, z_nt1, gh_nt0, gh_nt1 ; agi2: gi_n per nt
    f32x4 acc6[6], agi2[2];
#pragma unroll
    for (int q = 0; q < 6; q++) acc6[q] = (f32x4){0.f, 0.f, 0.f, 0.f};
    agi2[0] = (f32x4){0.f, 0.f, 0.f, 0.f};
    agi2[1] = (f32x4){0.f, 0.f, 0.f, 0.f};

#pragma unroll
    for (int p = 0; p < 16; p++) {
      RING_WAIT();  // vmcnt(8): position p (issued 3 ago) complete
      if (p == 0) {
        // convert x(t) (landed in xbuf[t&1] last step) to bf16 A-fragments
        const float* xb = &xbuf[t & 1][0];
        f32x4 a0 = *(const f32x4*)&xb[(2 * g) * 64 + c * 4];
        f32x4 a1 = *(const f32x4*)&xb[(2 * g + 1) * 64 + c * 4];
        f32x4 b0 = *(const f32x4*)&xb[(8 + 2 * g) * 64 + c * 4];
        f32x4 b1v = *(const f32x4*)&xb[(9 + 2 * g) * 64 + c * 4];
#pragma unroll
        for (int j = 0; j < 4; j++) {
          xf0[j] = (__bf16)a0[j];
          xf0[4 + j] = (__bf16)a1[j];
          xf1[j] = (__bf16)b0[j];
          xf1[4 + j] = (__bf16)b1v[j];
        }
      }
      if (p < 12) {
        // whh chunk: gate p>>2 (0=r,1=z,2=n-gh), nt = (p&3)>>1, kb0 = (p&1)*4
        const int gate = p >> 2, nt = (p & 3) >> 1, kb0 = (p & 1) * 4;
        const int ai = (gate < 2) ? gate * 2 + nt : 4 + nt;
        const __bf16* sb = slots + (p % 3) * 16384 + wv * 2048 + l * 8;
#pragma unroll
        for (int f = 0; f < 4; f++) {
          bf16x8 wf = *(const bf16x8*)(sb + f * 512);
          bf16x8 ofr = *(const bf16x8*)&o_fr[((kb0 + f) * 64 + l) * 8];
          acc6[ai] = mfma_bf16(ofr, wf, acc6[ai]);
        }
      } else if (p < 15) {
        // wih chunk: gate p-12; f: nt=f>>1, kb=f&1
        const int gg = p - 12;
        const __bf16* sb = slots + (p % 3) * 16384 + wv * 2048 + l * 8;
#pragma unroll
        for (int f = 0; f < 4; f++) {
          bf16x8 wf = *(const bf16x8*)(sb + f * 512);
          if (gg < 2)
            acc6[gg * 2 + (f >> 1)] = mfma_bf16((f & 1) ? xf1 : xf0, wf, acc6[gg * 2 + (f >> 1)]);
          else
            agi2[f >> 1] = mfma_bf16((f & 1) ? xf1 : xf0, wf, agi2[f >> 1]);
        }
      }
      // slot p%3 fully consumed (values in regs) before re-issuing into it
      asm volatile("s_waitcnt lgkmcnt(0)" ::: "memory");
      __builtin_amdgcn_sched_barrier(0);
      {
        const int k = (p + 3) & 15;
        if (k == 15) {
          ISSUE_X(t + 1);
        } else {
          ISSUE_W(k);
        }
      }
    }

    // ---- nonlinearity + state update
#pragma unroll
    for (int nt = 0; nt < 2; nt++) {
#pragma unroll
      for (int r = 0; r < 4; r++) {
        float rg = fast_sigmoid(acc6[nt][r] + brz[nt]);
        float zg = fast_sigmoid(acc6[2 + nt][r] + brz[2 + nt]);
        float ng = fast_tanh(agi2[nt][r] + bin[nt] + rg * (acc6[4 + nt][r] + bhn[nt]));
        float hn = (1.f - zg) * ng + zg * hreg[nt][r];
        hreg[nt][r] = hn;
        if (t == len4[r] - 1) hlast[4 * g + r][32 * wv + 16 * nt + c] = hn;
        h_fr[wbase + (r + 32 * nt) * 8] = (__bf16)hn;
      }
    }
    BAR();
  }

  // ---- Output: out = h_last @ w_out^T + b_out (bf16 hi/lo split, ~fp32)
  const bf16x8* woh = (const bf16x8*)wouth;
  const bf16x8* wol = (const bf16x8*)woutl;
  f32x4 oa[2] = {{0.f, 0.f, 0.f, 0.f}, {0.f, 0.f, 0.f, 0.f}};
#pragma unroll
  for (int kb = 0; kb < 8; kb++) {
    f32x4 v0 = *(const f32x4*)&hlast[c][kb * 32 + 8 * g];
    f32x4 v1 = *(const f32x4*)&hlast[c][kb * 32 + 8 * g + 4];
    bf16x8 hhi, hlo;
#pragma unroll
    for (int j = 0; j < 4; j++) {
      __bf16 p = (__bf16)v0[j]; hhi[j] = p; hlo[j] = (__bf16)(v0[j] - (float)p);
      __bf16 q = (__bf16)v1[j]; hhi[4 + j] = q; hlo[4 + j] = (__bf16)(v1[j] - (float)q);
    }
#pragma unroll
    for (int nt = 0; nt < 2; nt++) {
      int tile = 2 * wv + nt;
      oa[nt] = mfma_bf16(hhi, woh[(tile * 8 + kb) * 64 + l], oa[nt]);
      oa[nt] = mfma_bf16(hlo, woh[(tile * 8 + kb) * 64 + l], oa[nt]);
      oa[nt] = mfma_bf16(hhi, wol[(tile * 8 + kb) * 64 + l], oa[nt]);
    }
  }
#pragma unroll
  for (int nt = 0; nt < 2; nt++)
#pragma unroll
    for (int r = 0; r < 4; r++)
      out[(size_t)(m0 + 4 * g + r) * Hn + 32 * wv + 16 * nt + c] = oa[nt][r] + bo[nt];
}

extern "C" void kernel_launch(void* const* d_in, const int* in_sizes, int n_in,
                              void* d_out, int out_size, void* d_ws, size_t ws_size,
                              hipStream_t stream) {
  const float* x = (const float*)d_in[0];
  const float* tps = (const float*)d_in[1];
  const float* mask = (const float*)d_in[2];
  const float* w_ih = (const float*)d_in[3];
  const float* w_hh = (const float*)d_in[4];
  const float* b_ih = (const float*)d_in[5];
  const float* b_hh = (const float*)d_in[6];
  const float* w1 = (const float*)d_in[7];
  const float* b1 = (const float*)d_in[8];
  const float* w2 = (const float*)d_in[9];
  const float* b2 = (const float*)d_in[10];
  const float* w_out = (const float*)d_in[11];
  const float* b_out = (const float*)d_in[12];

  char* ws = (char*)d_ws;
  __bf16* w1p = (__bf16*)(ws + 0);         // 131072 B
  __bf16* w2p = (__bf16*)(ws + 131072);    // 131072 B
  __bf16* whhp = (__bf16*)(ws + 262144);   // 393216 B
  __bf16* wihp = (__bf16*)(ws + 655360);   // 98304 B
  __bf16* wouth = (__bf16*)(ws + 753664);  // 131072 B
  __bf16* woutl = (__bf16*)(ws + 884736);  // 131072 B  (total < 1 MB)

  pack_w<<<(256 * 256 + 255) / 256, 256, 0, stream>>>(w1, w1p, 256, 256);
  pack_w<<<(256 * 256 + 255) / 256, 256, 0, stream>>>(w2, w2p, 256, 256);
  pack_w<<<(768 * 256 + 255) / 256, 256, 0, stream>>>(w_hh, whhp, 768, 256);
  pack_w<<<(768 * 64 + 255) / 256, 256, 0, stream>>>(w_ih, wihp, 768, 64);
  pack_w_hilo<<<(256 * 256 + 255) / 256, 256, 0, stream>>>(w_out, wouth, woutl, 256, 256);

  gru_ode_kernel<<<32, 512, 0, stream>>>(x, tps, mask, b_ih, b_hh, b1, b2, b_out,
                                         w1p, w2p, whhp, wihp, wouth, woutl,
                                         (float*)d_out);
}